// Round 5
// baseline (496.029 us; speedup 1.0000x reference)
//
#include <hip/hip_runtime.h>

// ---------- problem constants ----------
#define CDIM   768
#define NSEQ   196
#define NVIEW  5
#define BN_TOT 6272       // B*N
#define SLAB   4816896    // BN_TOT*CDIM
#define WSLAB  589824     // CDIM*CDIM

typedef __attribute__((ext_vector_type(8))) short short8;  // 8 bf16 (4 VGPRs)
typedef __attribute__((ext_vector_type(4))) float f32x4;

// ---------- helpers ----------
__device__ __forceinline__ float bf_lo(unsigned u) { return __uint_as_float(u << 16); }
__device__ __forceinline__ float bf_hi(unsigned u) { return __uint_as_float(u & 0xffff0000u); }
__device__ __forceinline__ unsigned short f2bf(float f) {
  unsigned u = __float_as_uint(f);
  return (unsigned short)((u + 0x7fffu + ((u >> 16) & 1u)) >> 16);  // RNE
}
__device__ __forceinline__ unsigned pack2(float f0, float f1) {
  return (unsigned)f2bf(f0) | ((unsigned)f2bf(f1) << 16);
}
__device__ __forceinline__ float ftanh(float x) {
  x = fminf(fmaxf(x, -10.f), 10.f);
  float e = __expf(2.f * x);
  return (e - 1.f) / (e + 1.f);
}
__device__ __forceinline__ void async_cp16(const void* g, void* l) {
  __builtin_amdgcn_global_load_lds((const __attribute__((address_space(1))) unsigned*)g,
                                   (__attribute__((address_space(3))) unsigned*)l, 16, 0, 0);
}

// ---------- weight transpose fp32 -> bf16: 7 matrices of 768x768 ----------
__global__ __launch_bounds__(256) void k_tr(const float* __restrict__ wv,
                                            const float* __restrict__ w1,
                                            unsigned short* __restrict__ wvT,
                                            unsigned short* __restrict__ w1aT,
                                            unsigned short* __restrict__ w1bT) {
  __shared__ float tile[32][33];
  const int m = blockIdx.z;
  const float* src;
  unsigned short* dst;
  if (m < NVIEW)      { src = wv + (size_t)m * WSLAB; dst = wvT + (size_t)m * WSLAB; }
  else if (m == NVIEW){ src = w1;                     dst = w1aT; }
  else                { src = w1 + WSLAB;             dst = w1bT; }
  const int tx = threadIdx.x, ty = threadIdx.y;
  const int x0 = blockIdx.x * 32, y0 = blockIdx.y * 32;
#pragma unroll
  for (int i = 0; i < 4; ++i)
    tile[ty + i * 8][tx] = src[(size_t)(y0 + ty + i * 8) * CDIM + x0 + tx];
  __syncthreads();
#pragma unroll
  for (int i = 0; i < 4; ++i)
    dst[(size_t)(x0 + ty + i * 8) * CDIM + y0 + tx] = f2bf(tile[tx][ty + i * 8]);
}

// ---------- single pass over x: xb[v][bn][c] = bf16(x), cb = mean over v ----------
__global__ __launch_bounds__(192) void k_cvt_mean(const float* __restrict__ x,
                                                  unsigned short* __restrict__ xb,
                                                  unsigned short* __restrict__ cb) {
  const int bn = blockIdx.x;
  const int b = bn / NSEQ, n = bn % NSEQ;
  const int h = threadIdx.x * 4;
  const float* xp = x + ((size_t)(b * NVIEW) * NSEQ + n) * CDIM + h;
  float s0 = 0, s1 = 0, s2 = 0, s3 = 0;
#pragma unroll
  for (int v = 0; v < NVIEW; ++v) {
    float4 p = *(const float4*)(xp + (size_t)v * (NSEQ * CDIM));
    s0 += p.x; s1 += p.y; s2 += p.z; s3 += p.w;
    uint2 q; q.x = pack2(p.x, p.y); q.y = pack2(p.z, p.w);
    *(uint2*)(xb + ((size_t)v * BN_TOT + bn) * CDIM + h) = q;
  }
  uint2 o;
  o.x = pack2(s0 * 0.2f, s1 * 0.2f);
  o.y = pack2(s2 * 0.2f, s3 * 0.2f);
  *(uint2*)(cb + (size_t)bn * CDIM + h) = o;
}

// ---------- dual-output 128x128 bf16 MFMA GEMM (Bt layout [Nout,K]) ----------
// MODE 0 (shared A, grid 6,49,5):  A=P0+z*SLAB; B0=P1+z*WSLAB; B1=P2; C0=Q0+z*SLAB; C1=Q1+z*SLAB
// MODE 1 (shared B, grid 6,49,3):  B=P2; A0=P0+2z*SLAB; A1=(z<2 ? P0+(2z+1)*SLAB : P1);
//                                  C0=Q0+2z*SLAB; C1=(z<2 ? Q0+(2z+1)*SLAB : Q1)
template <int MODE>
__global__ __launch_bounds__(256) void gemm_dual(const unsigned short* __restrict__ P0,
                                                 const unsigned short* __restrict__ P1,
                                                 const unsigned short* __restrict__ P2,
                                                 unsigned short* __restrict__ Q0,
                                                 unsigned short* __restrict__ Q1) {
  __shared__ __align__(16) unsigned short ldsX[128 * 32];  // row tile (A / A0)
  __shared__ __align__(16) unsigned short ldsY[128 * 32];  // col tile (B0 / B)
  __shared__ __align__(16) unsigned short ldsZ[128 * 32];  // B1 / A1
  const int t = threadIdx.x, w = t >> 6, lane = t & 63;
  const int lr = lane & 15, lq = lane >> 4;
  const int wm = (w >> 1) * 64, wn = (w & 1) * 64;
  const int nt = blockIdx.x, mt = blockIdx.y, z = blockIdx.z;
  const unsigned short *g0, *g1, *g2;
  unsigned short *C0, *C1;
  if (MODE == 0) {
    g0 = P0 + (size_t)z * SLAB;      // A rows
    g1 = P1 + (size_t)z * WSLAB;     // B0 rows (cols of C)
    g2 = P2;                         // B1 rows
    C0 = Q0 + (size_t)z * SLAB;
    C1 = Q1 + (size_t)z * SLAB;
  } else {
    g0 = P0 + (size_t)(2 * z) * SLAB;                       // A0
    g1 = P2;                                                // B
    g2 = (z < 2) ? P0 + (size_t)(2 * z + 1) * SLAB : P1;    // A1
    C0 = Q0 + (size_t)(2 * z) * SLAB;
    C1 = (z < 2) ? Q0 + (size_t)(2 * z + 1) * SLAB : Q1;
  }
  const int r2 = (MODE == 0) ? nt : mt;  // g2's 128-row tile index
  const unsigned short* p0 = g0 + ((size_t)mt * 128 + (t >> 2)) * CDIM + (t & 3) * 8;
  const unsigned short* p1 = g1 + ((size_t)nt * 128 + (t >> 2)) * CDIM + (t & 3) * 8;
  const unsigned short* p2 = g2 + ((size_t)r2 * 128 + (t >> 2)) * CDIM + (t & 3) * 8;

  f32x4 acc0[4][4] = {}, acc1[4][4] = {};
  for (int k0 = 0; k0 < CDIM; k0 += 32) {
    __syncthreads();  // previous tile's ds_reads done before overwrite
    async_cp16(p0 + k0, &ldsX[w * 512]);
    async_cp16(p0 + (size_t)64 * CDIM + k0, &ldsX[2048 + w * 512]);
    async_cp16(p1 + k0, &ldsY[w * 512]);
    async_cp16(p1 + (size_t)64 * CDIM + k0, &ldsY[2048 + w * 512]);
    async_cp16(p2 + k0, &ldsZ[w * 512]);
    async_cp16(p2 + (size_t)64 * CDIM + k0, &ldsZ[2048 + w * 512]);
    __syncthreads();  // drains vmcnt before s_barrier
    short8 fx[4], fy[4], fz[4];
#pragma unroll
    for (int i = 0; i < 4; ++i) fx[i] = *(const short8*)&ldsX[(wm + i * 16 + lr) * 32 + lq * 8];
#pragma unroll
    for (int j = 0; j < 4; ++j) fy[j] = *(const short8*)&ldsY[(wn + j * 16 + lr) * 32 + lq * 8];
#pragma unroll
    for (int j = 0; j < 4; ++j)
      fz[j] = *(const short8*)&ldsZ[(((MODE == 0 ? wn : wm) + j * 16 + lr)) * 32 + lq * 8];
#pragma unroll
    for (int i = 0; i < 4; ++i)
#pragma unroll
      for (int j = 0; j < 4; ++j) {
        acc0[i][j] = __builtin_amdgcn_mfma_f32_16x16x32_bf16(fx[i], fy[j], acc0[i][j], 0, 0, 0);
        if (MODE == 0)
          acc1[i][j] = __builtin_amdgcn_mfma_f32_16x16x32_bf16(fx[i], fz[j], acc1[i][j], 0, 0, 0);
        else
          acc1[i][j] = __builtin_amdgcn_mfma_f32_16x16x32_bf16(fz[i], fy[j], acc1[i][j], 0, 0, 0);
      }
  }
#pragma unroll
  for (int i = 0; i < 4; ++i)
#pragma unroll
    for (int j = 0; j < 4; ++j) {
      const int gc = nt * 128 + wn + j * 16 + lr;
      const int gr = mt * 128 + wm + i * 16 + lq * 4;   // C/D: row=(lane>>4)*4+reg, col=lane&15
#pragma unroll
      for (int r = 0; r < 4; ++r) {
        C0[(size_t)(gr + r) * CDIM + gc] = f2bf(acc0[i][j][r]);
        C1[(size_t)(gr + r) * CDIM + gc] = f2bf(acc1[i][j][r]);
      }
    }
}

// ---------- fully fused routing loop: 3x (scores -> softmax -> weighted sum), pointwise in bn ----------
__global__ __launch_bounds__(192) void k_iter3(const unsigned short* __restrict__ xw1b,
                                               const unsigned short* __restrict__ cw1,
                                               const unsigned short* __restrict__ pw1b,
                                               const unsigned short* __restrict__ projb,
                                               const float* __restrict__ b1,
                                               const float* __restrict__ w2,
                                               float* __restrict__ outc,
                                               float* __restrict__ outr) {
  __shared__ float red[3][NVIEW];
  __shared__ float aa[NVIEW];
  const int bn = blockIdx.x, t = threadIdx.x, wid = t >> 6, lane = t & 63;
  const int h = t * 4;
  const float4 bv = *(const float4*)(b1 + h);
  const float4 wv = *(const float4*)(w2 + h);
  float cw[4];
  { uint2 c = *(const uint2*)(cw1 + (size_t)bn * CDIM + h);
    cw[0] = bf_lo(c.x); cw[1] = bf_hi(c.x); cw[2] = bf_lo(c.y); cw[3] = bf_hi(c.y); }
  float xw[NVIEW][4], pf[NVIEW][4];
#pragma unroll
  for (int v = 0; v < NVIEW; ++v) {
    uint2 q = *(const uint2*)(xw1b + ((size_t)v * BN_TOT + bn) * CDIM + h);
    xw[v][0] = bf_lo(q.x) + bv.x; xw[v][1] = bf_hi(q.x) + bv.y;
    xw[v][2] = bf_lo(q.y) + bv.z; xw[v][3] = bf_hi(q.y) + bv.w;
    uint2 p = *(const uint2*)(pw1b + ((size_t)v * BN_TOT + bn) * CDIM + h);
    pf[v][0] = bf_lo(p.x); pf[v][1] = bf_hi(p.x);
    pf[v][2] = bf_lo(p.y); pf[v][3] = bf_hi(p.y);
  }
  for (int it = 0; it < 3; ++it) {
    float part[NVIEW];
#pragma unroll
    for (int v = 0; v < NVIEW; ++v) {
      float p;
      p = wv.x * ftanh(xw[v][0] + cw[0]);
      p = fmaf(wv.y, ftanh(xw[v][1] + cw[1]), p);
      p = fmaf(wv.z, ftanh(xw[v][2] + cw[2]), p);
      p = fmaf(wv.w, ftanh(xw[v][3] + cw[3]), p);
      part[v] = p;
    }
#pragma unroll
    for (int off = 32; off > 0; off >>= 1)
#pragma unroll
      for (int v = 0; v < NVIEW; ++v) part[v] += __shfl_down(part[v], off);
    if (lane == 0)
#pragma unroll
      for (int v = 0; v < NVIEW; ++v) red[wid][v] = part[v];
    __syncthreads();
    if (t == 0) {
      float s[NVIEW];
#pragma unroll
      for (int v = 0; v < NVIEW; ++v) s[v] = red[0][v] + red[1][v] + red[2][v];
      float m = s[0];
#pragma unroll
      for (int v = 1; v < NVIEW; ++v) m = fmaxf(m, s[v]);
      float a[NVIEW], sum = 0.f;
#pragma unroll
      for (int v = 0; v < NVIEW; ++v) { a[v] = __expf(s[v] - m); sum += a[v]; }
      const float inv = 1.f / sum;
#pragma unroll
      for (int v = 0; v < NVIEW; ++v) { a[v] *= inv; aa[v] = a[v]; }
      if (it == 2) {
        float ent = 0.f;
#pragma unroll
        for (int v = 0; v < NVIEW; ++v) ent -= a[v] * logf(a[v] + 1e-8f);
        outr[bn] = 1.f - ent * 0.6213349345596119f;  // 1/ln(5)
      }
    }
    __syncthreads();
    if (it < 2) {
      float n0 = 0, n1 = 0, n2 = 0, n3 = 0;
#pragma unroll
      for (int v = 0; v < NVIEW; ++v) {
        const float av = aa[v];
        n0 = fmaf(av, pf[v][0], n0); n1 = fmaf(av, pf[v][1], n1);
        n2 = fmaf(av, pf[v][2], n2); n3 = fmaf(av, pf[v][3], n3);
      }
      cw[0] = n0; cw[1] = n1; cw[2] = n2; cw[3] = n3;
    } else {
      float r0 = 0, r1 = 0, r2 = 0, r3 = 0;
#pragma unroll
      for (int v = 0; v < NVIEW; ++v) {
        const float av = aa[v];
        uint2 p = *(const uint2*)(projb + ((size_t)v * BN_TOT + bn) * CDIM + h);
        r0 = fmaf(av, bf_lo(p.x), r0); r1 = fmaf(av, bf_hi(p.x), r1);
        r2 = fmaf(av, bf_lo(p.y), r2); r3 = fmaf(av, bf_hi(p.y), r3);
      }
      float4 of; of.x = r0; of.y = r1; of.z = r2; of.w = r3;
      *(float4*)(outc + (size_t)bn * CDIM + h) = of;
    }
  }
}

extern "C" void kernel_launch(void* const* d_in, const int* in_sizes, int n_in,
                              void* d_out, int out_size, void* d_ws, size_t ws_size,
                              hipStream_t stream) {
  (void)in_sizes; (void)n_in; (void)out_size; (void)ws_size;
  const float* x  = (const float*)d_in[0];   // [B,V,N,C] fp32
  const float* wv = (const float*)d_in[1];   // [V,C,C]
  const float* w1 = (const float*)d_in[2];   // [2C,H]
  const float* b1 = (const float*)d_in[3];   // [H]
  const float* w2 = (const float*)d_in[4];   // [H,1]
  // d_in[5] = b2: uniform shift over views -> softmax-invariant, unused.

  unsigned short* ws   = (unsigned short*)d_ws;          // peak ~220 MB (ws ~385 MB)
  unsigned short* wvT  = ws;                             //  2,949,120
  unsigned short* w1aT = ws + 2949120;                   //    589,824
  unsigned short* w1bT = ws + 3538944;                   //    589,824
  unsigned short* xb   = ws + 4128768;                   // 24,084,480  [V,BN,C] bf16
  unsigned short* projb= ws + 28213248;                  // 24,084,480  [V,BN,C]
  unsigned short* xw1b = ws + 52297728;                  // 24,084,480  [V,BN,C]
  unsigned short* pw1b = ws + 76382208;                  // 24,084,480  [V,BN,C]
  unsigned short* cb   = ws + 100466688;                 //  4,816,896  [BN,C]
  unsigned short* cw1  = ws + 105283584;                 //  4,816,896  [BN,C]

  float* outc = (float*)d_out;                           // c [B,N,C] fp32
  float* outr = outc + SLAB;                             // r [B,N]   fp32

  k_tr<<<dim3(24, 24, 7), dim3(32, 8), 0, stream>>>(wv, w1, wvT, w1aT, w1bT);
  k_cvt_mean<<<BN_TOT, 192, 0, stream>>>(x, xb, cb);
  // shared-A dual: proj_v = x_v @ wv_v ; xw1_v = x_v @ w1[:C]
  gemm_dual<0><<<dim3(6, 49, NVIEW), 256, 0, stream>>>(xb, wvT, w1aT, projb, xw1b);
  // shared-B dual: pw1b_v = proj_v @ w1b (pairs) ; cw1_0 = c_0 @ w1b (paired with pw1b_4)
  gemm_dual<1><<<dim3(6, 49, 3), 256, 0, stream>>>(projb, cb, w1bT, pw1b, cw1);
  // fused routing: 3 iterations pointwise in (b,n), no GEMMs (linearity of @w1b)
  k_iter3<<<BN_TOT, 192, 0, stream>>>(xw1b, cw1, pw1b, projb, b1, w2, outc, outr);
}

// Round 7
// 407.865 us; speedup vs baseline: 1.2162x; 1.2162x over previous
//
#include <hip/hip_runtime.h>

// ---------- problem constants ----------
#define CDIM   768
#define NSEQ   196
#define NVIEW  5
#define BN_TOT 6272       // B*N
#define SLAB   4816896    // BN_TOT*CDIM
#define WSLAB  589824     // CDIM*CDIM

typedef __attribute__((ext_vector_type(8))) short short8;  // 8 bf16 (4 VGPRs)
typedef __attribute__((ext_vector_type(4))) float f32x4;

// ---------- helpers ----------
__device__ __forceinline__ float bf_lo(unsigned u) { return __uint_as_float(u << 16); }
__device__ __forceinline__ float bf_hi(unsigned u) { return __uint_as_float(u & 0xffff0000u); }
__device__ __forceinline__ unsigned short f2bf(float f) {
  unsigned u = __float_as_uint(f);
  return (unsigned short)((u + 0x7fffu + ((u >> 16) & 1u)) >> 16);  // RNE
}
__device__ __forceinline__ unsigned pack2(float f0, float f1) {
  return (unsigned)f2bf(f0) | ((unsigned)f2bf(f1) << 16);
}
__device__ __forceinline__ float ftanh(float x) {
  x = fminf(fmaxf(x, -10.f), 10.f);
  float e = __expf(2.f * x);
  return (e - 1.f) / (e + 1.f);
}
__device__ __forceinline__ void async_cp16(const void* g, void* l) {
  __builtin_amdgcn_global_load_lds((const __attribute__((address_space(1))) unsigned*)g,
                                   (__attribute__((address_space(3))) unsigned*)l, 16, 0, 0);
}

// ---------- weight transpose fp32 -> bf16: 7 matrices of 768x768 ----------
// m<5: wvT[v][d][c]=wv[v][c][d]; m=5: w1aT[h][c]=w1[c][h]; m=6: w1bT[h][c]=w1[C+c][h]
__global__ __launch_bounds__(256) void k_tr(const float* __restrict__ wv,
                                            const float* __restrict__ w1,
                                            unsigned short* __restrict__ wvT,
                                            unsigned short* __restrict__ w1aT,
                                            unsigned short* __restrict__ w1bT) {
  __shared__ float tile[32][33];
  const int m = blockIdx.z;
  const float* src;
  unsigned short* dst;
  if (m < NVIEW)      { src = wv + (size_t)m * WSLAB; dst = wvT + (size_t)m * WSLAB; }
  else if (m == NVIEW){ src = w1;                     dst = w1aT; }
  else                { src = w1 + WSLAB;             dst = w1bT; }
  const int tx = threadIdx.x, ty = threadIdx.y;
  const int x0 = blockIdx.x * 32, y0 = blockIdx.y * 32;
#pragma unroll
  for (int i = 0; i < 4; ++i)
    tile[ty + i * 8][tx] = src[(size_t)(y0 + ty + i * 8) * CDIM + x0 + tx];
  __syncthreads();
#pragma unroll
  for (int i = 0; i < 4; ++i)
    dst[(size_t)(x0 + ty + i * 8) * CDIM + y0 + tx] = f2bf(tile[tx][ty + i * 8]);
}

// ---------- single pass over x: xb[v][bn][c] = bf16(x), cb = mean over v ----------
__global__ __launch_bounds__(192) void k_cvt_mean(const float* __restrict__ x,
                                                  unsigned short* __restrict__ xb,
                                                  unsigned short* __restrict__ cb) {
  const int bn = blockIdx.x;
  const int b = bn / NSEQ, n = bn % NSEQ;
  const int h = threadIdx.x * 4;
  const float* xp = x + ((size_t)(b * NVIEW) * NSEQ + n) * CDIM + h;
  float s0 = 0, s1 = 0, s2 = 0, s3 = 0;
#pragma unroll
  for (int v = 0; v < NVIEW; ++v) {
    float4 p = *(const float4*)(xp + (size_t)v * (NSEQ * CDIM));
    s0 += p.x; s1 += p.y; s2 += p.z; s3 += p.w;
    uint2 q; q.x = pack2(p.x, p.y); q.y = pack2(p.z, p.w);
    *(uint2*)(xb + ((size_t)v * BN_TOT + bn) * CDIM + h) = q;
  }
  uint2 o;
  o.x = pack2(s0 * 0.2f, s1 * 0.2f);
  o.y = pack2(s2 * 0.2f, s3 * 0.2f);
  *(uint2*)(cb + (size_t)bn * CDIM + h) = o;
}

// ---------- 128x128-tile bf16 MFMA GEMM, Bt [Nout,K], single accumulator (68 VGPR class) ----------
// MODE 0 (launch A, grid 6,49,11): z<5: proj_v = xb_v @ wvT_v -> projb ;
//   z in [5,10): xw1_v = xb_v @ w1aT -> xw1b ; z==10: cw1_0 = cb @ w1bT -> cw1
//   P0=xb P1=cb P2=wvT P3=w1aT P4=w1bT ; Q0=projb Q1=xw1b Q2=cw1
// MODE 1 (launch B, grid 6,49,5): pw1b_v = projb_v @ w1bT -> Q0 (aliased onto xb; xb is dead)
//   P0=projb P4=w1bT ; Q0=pw1b
template <int MODE>
__global__ __launch_bounds__(256) void gemm_bt(const unsigned short* __restrict__ P0,
                                               const unsigned short* __restrict__ P1,
                                               const unsigned short* __restrict__ P2,
                                               const unsigned short* __restrict__ P3,
                                               const unsigned short* __restrict__ P4,
                                               unsigned short* __restrict__ Q0,
                                               unsigned short* __restrict__ Q1,
                                               unsigned short* __restrict__ Q2) {
  __shared__ __align__(16) unsigned short ldsA[128 * 32];
  __shared__ __align__(16) unsigned short ldsB[128 * 32];
  const int t = threadIdx.x, w = t >> 6, lane = t & 63;
  const int lr = lane & 15, lq = lane >> 4;
  const int wm = (w >> 1) * 64, wn = (w & 1) * 64;
  const int nt = blockIdx.x, mt = blockIdx.y, z = blockIdx.z;
  const unsigned short *A, *Bt;
  unsigned short* C;
  if (MODE == 0) {
    if (z == 10) { A = P1; Bt = P4; C = Q2; }
    else if (z < 5)  { A = P0 + (size_t)z * SLAB;       Bt = P2 + (size_t)z * WSLAB; C = Q0 + (size_t)z * SLAB; }
    else             { A = P0 + (size_t)(z - 5) * SLAB; Bt = P3;                     C = Q1 + (size_t)(z - 5) * SLAB; }
  } else {
    A = P0 + (size_t)z * SLAB; Bt = P4; C = Q0 + (size_t)z * SLAB;
  }

  const unsigned short* ga0 = A + ((size_t)mt * 128 + (t >> 2)) * CDIM + (t & 3) * 8;
  const unsigned short* ga1 = ga0 + (size_t)64 * CDIM;
  const unsigned short* gb0 = Bt + ((size_t)nt * 128 + (t >> 2)) * CDIM + (t & 3) * 8;
  const unsigned short* gb1 = gb0 + (size_t)64 * CDIM;

  f32x4 acc[4][4] = {};
  for (int k0 = 0; k0 < CDIM; k0 += 32) {
    __syncthreads();  // previous tile's ds_reads done before overwrite
    async_cp16(ga0 + k0, &ldsA[w * 512]);
    async_cp16(ga1 + k0, &ldsA[2048 + w * 512]);
    async_cp16(gb0 + k0, &ldsB[w * 512]);
    async_cp16(gb1 + k0, &ldsB[2048 + w * 512]);
    __syncthreads();  // drains vmcnt before s_barrier
    short8 af[4], bv[4];
#pragma unroll
    for (int i = 0; i < 4; ++i) af[i] = *(const short8*)&ldsA[(wm + i * 16 + lr) * 32 + lq * 8];
#pragma unroll
    for (int j = 0; j < 4; ++j) bv[j] = *(const short8*)&ldsB[(wn + j * 16 + lr) * 32 + lq * 8];
#pragma unroll
    for (int i = 0; i < 4; ++i)
#pragma unroll
      for (int j = 0; j < 4; ++j)
        acc[i][j] = __builtin_amdgcn_mfma_f32_16x16x32_bf16(af[i], bv[j], acc[i][j], 0, 0, 0);
  }
#pragma unroll
  for (int i = 0; i < 4; ++i)
#pragma unroll
    for (int j = 0; j < 4; ++j) {
      const int gc = nt * 128 + wn + j * 16 + lr;
      const int gr = mt * 128 + wm + i * 16 + lq * 4;   // C/D: row=(lane>>4)*4+reg, col=lane&15
#pragma unroll
      for (int r = 0; r < 4; ++r)
        C[(size_t)(gr + r) * CDIM + gc] = f2bf(acc[i][j][r]);
    }
}

// ---------- fully fused routing loop: 3x (scores -> softmax -> weighted sum), pointwise in bn ----------
__global__ __launch_bounds__(192) void k_iter3(const unsigned short* __restrict__ xw1b,
                                               const unsigned short* __restrict__ cw1,
                                               const unsigned short* __restrict__ pw1b,
                                               const unsigned short* __restrict__ projb,
                                               const float* __restrict__ b1,
                                               const float* __restrict__ w2,
                                               float* __restrict__ outc,
                                               float* __restrict__ outr) {
  __shared__ float red[3][NVIEW];
  __shared__ float aa[NVIEW];
  const int bn = blockIdx.x, t = threadIdx.x, wid = t >> 6, lane = t & 63;
  const int h = t * 4;
  const float4 bv = *(const float4*)(b1 + h);
  const float4 wv = *(const float4*)(w2 + h);
  float cw[4];
  { uint2 c = *(const uint2*)(cw1 + (size_t)bn * CDIM + h);
    cw[0] = bf_lo(c.x); cw[1] = bf_hi(c.x); cw[2] = bf_lo(c.y); cw[3] = bf_hi(c.y); }
  float xw[NVIEW][4], pf[NVIEW][4];
#pragma unroll
  for (int v = 0; v < NVIEW; ++v) {
    uint2 q = *(const uint2*)(xw1b + ((size_t)v * BN_TOT + bn) * CDIM + h);
    xw[v][0] = bf_lo(q.x) + bv.x; xw[v][1] = bf_hi(q.x) + bv.y;
    xw[v][2] = bf_lo(q.y) + bv.z; xw[v][3] = bf_hi(q.y) + bv.w;
    uint2 p = *(const uint2*)(pw1b + ((size_t)v * BN_TOT + bn) * CDIM + h);
    pf[v][0] = bf_lo(p.x); pf[v][1] = bf_hi(p.x);
    pf[v][2] = bf_lo(p.y); pf[v][3] = bf_hi(p.y);
  }
  for (int it = 0; it < 3; ++it) {
    float part[NVIEW];
#pragma unroll
    for (int v = 0; v < NVIEW; ++v) {
      float p;
      p = wv.x * ftanh(xw[v][0] + cw[0]);
      p = fmaf(wv.y, ftanh(xw[v][1] + cw[1]), p);
      p = fmaf(wv.z, ftanh(xw[v][2] + cw[2]), p);
      p = fmaf(wv.w, ftanh(xw[v][3] + cw[3]), p);
      part[v] = p;
    }
#pragma unroll
    for (int off = 32; off > 0; off >>= 1)
#pragma unroll
      for (int v = 0; v < NVIEW; ++v) part[v] += __shfl_down(part[v], off);
    if (lane == 0)
#pragma unroll
      for (int v = 0; v < NVIEW; ++v) red[wid][v] = part[v];
    __syncthreads();
    if (t == 0) {
      float s[NVIEW];
#pragma unroll
      for (int v = 0; v < NVIEW; ++v) s[v] = red[0][v] + red[1][v] + red[2][v];
      float m = s[0];
#pragma unroll
      for (int v = 1; v < NVIEW; ++v) m = fmaxf(m, s[v]);
      float a[NVIEW], sum = 0.f;
#pragma unroll
      for (int v = 0; v < NVIEW; ++v) { a[v] = __expf(s[v] - m); sum += a[v]; }
      const float inv = 1.f / sum;
#pragma unroll
      for (int v = 0; v < NVIEW; ++v) { a[v] *= inv; aa[v] = a[v]; }
      if (it == 2) {
        float ent = 0.f;
#pragma unroll
        for (int v = 0; v < NVIEW; ++v) ent -= a[v] * logf(a[v] + 1e-8f);
        outr[bn] = 1.f - ent * 0.6213349345596119f;  // 1/ln(5)
      }
    }
    __syncthreads();
    if (it < 2) {
      float n0 = 0, n1 = 0, n2 = 0, n3 = 0;
#pragma unroll
      for (int v = 0; v < NVIEW; ++v) {
        const float av = aa[v];
        n0 = fmaf(av, pf[v][0], n0); n1 = fmaf(av, pf[v][1], n1);
        n2 = fmaf(av, pf[v][2], n2); n3 = fmaf(av, pf[v][3], n3);
      }
      cw[0] = n0; cw[1] = n1; cw[2] = n2; cw[3] = n3;
    } else {
      float r0 = 0, r1 = 0, r2 = 0, r3 = 0;
#pragma unroll
      for (int v = 0; v < NVIEW; ++v) {
        const float av = aa[v];
        uint2 p = *(const uint2*)(projb + ((size_t)v * BN_TOT + bn) * CDIM + h);
        r0 = fmaf(av, bf_lo(p.x), r0); r1 = fmaf(av, bf_hi(p.x), r1);
        r2 = fmaf(av, bf_lo(p.y), r2); r3 = fmaf(av, bf_hi(p.y), r3);
      }
      float4 of; of.x = r0; of.y = r1; of.z = r2; of.w = r3;
      *(float4*)(outc + (size_t)bn * CDIM + h) = of;
    }
  }
}

extern "C" void kernel_launch(void* const* d_in, const int* in_sizes, int n_in,
                              void* d_out, int out_size, void* d_ws, size_t ws_size,
                              hipStream_t stream) {
  (void)in_sizes; (void)n_in; (void)out_size; (void)ws_size;
  const float* x  = (const float*)d_in[0];   // [B,V,N,C] fp32
  const float* wv = (const float*)d_in[1];   // [V,C,C]
  const float* w1 = (const float*)d_in[2];   // [2C,H]
  const float* b1 = (const float*)d_in[3];   // [H]
  const float* w2 = (const float*)d_in[4];   // [H,1]
  // d_in[5] = b2: uniform shift over views -> softmax-invariant, unused.

  // workspace: 86,016,000 ushorts = 172 MB (round-5's 220 MB passed; round-6's 232 MB
  // corrupted state -> suspected d_ws overflow. Stay well below 220 MB.)
  unsigned short* ws   = (unsigned short*)d_ws;
  unsigned short* wvT  = ws;                             //  2,949,120  [V][d][c]
  unsigned short* w1aT = ws + 2949120;                   //    589,824
  unsigned short* w1bT = ws + 3538944;                   //    589,824
  unsigned short* xb   = ws + 4128768;                   // 24,084,480  [V,BN,C]; dead after GEMM A
  unsigned short* pw1b = ws + 4128768;                   //   (aliased onto xb)
  unsigned short* projb= ws + 28213248;                  // 24,084,480
  unsigned short* xw1b = ws + 52297728;                  // 24,084,480
  unsigned short* cb   = ws + 76382208;                  //  4,816,896
  unsigned short* cw1  = ws + 81199104;                  //  4,816,896  (end: 86,016,000)

  float* outc = (float*)d_out;                           // c [B,N,C] fp32
  float* outr = outc + SLAB;                             // r [B,N]   fp32

  k_tr<<<dim3(24, 24, 7), dim3(32, 8), 0, stream>>>(wv, w1, wvT, w1aT, w1bT);
  k_cvt_mean<<<BN_TOT, 192, 0, stream>>>(x, xb, cb);
  // GEMM A: proj_v = xb_v @ wv_v ; xw1_v = xb_v @ w1a ; cw1_0 = cb @ w1b  (11 units, 3234 blocks)
  gemm_bt<0><<<dim3(6, 49, 11), 256, 0, stream>>>(xb, cb, wvT, w1aT, w1bT, projb, xw1b, cw1);
  // GEMM B: pw1b_v = proj_v @ w1b  (xb memory reused; 1470 blocks)
  gemm_bt<1><<<dim3(6, 49, NVIEW), 256, 0, stream>>>(projb, nullptr, nullptr, nullptr, w1bT,
                                                     pw1b, nullptr, nullptr);
  // fused routing: 3 iterations pointwise in (b,n), no GEMMs (linearity of @w1b)
  k_iter3<<<BN_TOT, 192, 0, stream>>>(xw1b, cw1, pw1b, projb, b1, w2, outc, outr);
}

// Round 8
// 367.517 us; speedup vs baseline: 1.3497x; 1.1098x over previous
//
#include <hip/hip_runtime.h>

// ---------- problem constants ----------
#define CDIM   768
#define NSEQ   196
#define NVIEW  5
#define BN_TOT 6272       // B*N
#define SLAB   4816896    // BN_TOT*CDIM
#define WSLAB  589824     // CDIM*CDIM

typedef __attribute__((ext_vector_type(8))) short short8;  // 8 bf16 (4 VGPRs)
typedef __attribute__((ext_vector_type(4))) float f32x4;

// ---------- helpers ----------
__device__ __forceinline__ float bf_lo(unsigned u) { return __uint_as_float(u << 16); }
__device__ __forceinline__ float bf_hi(unsigned u) { return __uint_as_float(u & 0xffff0000u); }
__device__ __forceinline__ unsigned short f2bf(float f) {
  unsigned u = __float_as_uint(f);
  return (unsigned short)((u + 0x7fffu + ((u >> 16) & 1u)) >> 16);  // RNE
}
__device__ __forceinline__ unsigned pack2(float f0, float f1) {
  return (unsigned)f2bf(f0) | ((unsigned)f2bf(f1) << 16);
}
__device__ __forceinline__ float ftanh(float x) {
  x = fminf(fmaxf(x, -10.f), 10.f);
  float e = __expf(2.f * x);
  return (e - 1.f) / (e + 1.f);
}
__device__ __forceinline__ void async_cp16(const void* g, void* l) {
  __builtin_amdgcn_global_load_lds((const __attribute__((address_space(1))) unsigned*)g,
                                   (__attribute__((address_space(3))) unsigned*)l, 16, 0, 0);
}

// ---------- weight transpose fp32 -> bf16: 7 matrices of 768x768 ----------
// m<5: wvT[v][d][c]=wv[v][c][d]; m=5: w1aT[h][c]=w1[c][h]; m=6: w1bT[h][c]=w1[C+c][h]
__global__ __launch_bounds__(256) void k_tr(const float* __restrict__ wv,
                                            const float* __restrict__ w1,
                                            unsigned short* __restrict__ wvT,
                                            unsigned short* __restrict__ w1aT,
                                            unsigned short* __restrict__ w1bT) {
  __shared__ float tile[32][33];
  const int m = blockIdx.z;
  const float* src;
  unsigned short* dst;
  if (m < NVIEW)      { src = wv + (size_t)m * WSLAB; dst = wvT + (size_t)m * WSLAB; }
  else if (m == NVIEW){ src = w1;                     dst = w1aT; }
  else                { src = w1 + WSLAB;             dst = w1bT; }
  const int tx = threadIdx.x, ty = threadIdx.y;
  const int x0 = blockIdx.x * 32, y0 = blockIdx.y * 32;
#pragma unroll
  for (int i = 0; i < 4; ++i)
    tile[ty + i * 8][tx] = src[(size_t)(y0 + ty + i * 8) * CDIM + x0 + tx];
  __syncthreads();
#pragma unroll
  for (int i = 0; i < 4; ++i)
    dst[(size_t)(x0 + ty + i * 8) * CDIM + y0 + tx] = f2bf(tile[tx][ty + i * 8]);
}

// ---------- single pass over x: xb[v][bn][c] = bf16(x), cb = mean over v ----------
__global__ __launch_bounds__(192) void k_cvt_mean(const float* __restrict__ x,
                                                  unsigned short* __restrict__ xb,
                                                  unsigned short* __restrict__ cb) {
  const int bn = blockIdx.x;
  const int b = bn / NSEQ, n = bn % NSEQ;
  const int h = threadIdx.x * 4;
  const float* xp = x + ((size_t)(b * NVIEW) * NSEQ + n) * CDIM + h;
  float s0 = 0, s1 = 0, s2 = 0, s3 = 0;
#pragma unroll
  for (int v = 0; v < NVIEW; ++v) {
    float4 p = *(const float4*)(xp + (size_t)v * (NSEQ * CDIM));
    s0 += p.x; s1 += p.y; s2 += p.z; s3 += p.w;
    uint2 q; q.x = pack2(p.x, p.y); q.y = pack2(p.z, p.w);
    *(uint2*)(xb + ((size_t)v * BN_TOT + bn) * CDIM + h) = q;
  }
  uint2 o;
  o.x = pack2(s0 * 0.2f, s1 * 0.2f);
  o.y = pack2(s2 * 0.2f, s3 * 0.2f);
  *(uint2*)(cb + (size_t)bn * CDIM + h) = o;
}

// ---------- 128x128-tile bf16 MFMA GEMM, Bt [Nout,K], XCD-swizzled 1-D grid ----------
// Work decode (after swizzle): nt = work%6, mt = (work/6)%49, z = work/294.
// MODE 0 (TOTAL=3234): z<5: proj_v = xb_v @ wvT_v ; z in[5,10): xw1_v = xb_v @ w1aT ;
//   z==10: cw1_0 = cb @ w1bT.   P0=xb P1=cb P2=wvT P3=w1aT P4=w1bT ; Q0=projb Q1=xw1b Q2=cw1
// MODE 1 (TOTAL=1470): pw1b_z = projb_z @ w1bT.  P0=projb P4=w1bT ; Q0=pw1b
// Swizzle: xcd = bid&7 (assumes round-robin workgroup->XCD), slot = bid>>3;
// each XCD gets a CONTIGUOUS chunk with nt fastest -> the 6 blocks sharing an
// A-row-block are co-resident on one XCD -> A served from its L2, not HBM 6x.
template <int MODE, int TOTAL, int CHUNK>
__global__ __launch_bounds__(256, 4) void gemm_bt(const unsigned short* __restrict__ P0,
                                                  const unsigned short* __restrict__ P1,
                                                  const unsigned short* __restrict__ P2,
                                                  const unsigned short* __restrict__ P3,
                                                  const unsigned short* __restrict__ P4,
                                                  unsigned short* __restrict__ Q0,
                                                  unsigned short* __restrict__ Q1,
                                                  unsigned short* __restrict__ Q2) {
  const int bid = blockIdx.x;
  const int work = (bid & 7) * CHUNK + (bid >> 3);
  if (work >= TOTAL) return;
  const int nt = work % 6;
  const int wq = work / 6;
  const int mt = wq % 49, z = wq / 49;

  __shared__ __align__(16) unsigned short ldsA[128 * 32];
  __shared__ __align__(16) unsigned short ldsB[128 * 32];
  const int t = threadIdx.x, w = t >> 6, lane = t & 63;
  const int lr = lane & 15, lq = lane >> 4;
  const int wm = (w >> 1) * 64, wn = (w & 1) * 64;
  const unsigned short *A, *Bt;
  unsigned short* C;
  if (MODE == 0) {
    if (z == 10) { A = P1; Bt = P4; C = Q2; }
    else if (z < 5)  { A = P0 + (size_t)z * SLAB;       Bt = P2 + (size_t)z * WSLAB; C = Q0 + (size_t)z * SLAB; }
    else             { A = P0 + (size_t)(z - 5) * SLAB; Bt = P3;                     C = Q1 + (size_t)(z - 5) * SLAB; }
  } else {
    A = P0 + (size_t)z * SLAB; Bt = P4; C = Q0 + (size_t)z * SLAB;
  }

  const unsigned short* ga0 = A + ((size_t)mt * 128 + (t >> 2)) * CDIM + (t & 3) * 8;
  const unsigned short* ga1 = ga0 + (size_t)64 * CDIM;
  const unsigned short* gb0 = Bt + ((size_t)nt * 128 + (t >> 2)) * CDIM + (t & 3) * 8;
  const unsigned short* gb1 = gb0 + (size_t)64 * CDIM;

  f32x4 acc[4][4] = {};
  for (int k0 = 0; k0 < CDIM; k0 += 32) {
    __syncthreads();  // previous tile's ds_reads done before overwrite
    async_cp16(ga0 + k0, &ldsA[w * 512]);
    async_cp16(ga1 + k0, &ldsA[2048 + w * 512]);
    async_cp16(gb0 + k0, &ldsB[w * 512]);
    async_cp16(gb1 + k0, &ldsB[2048 + w * 512]);
    __syncthreads();  // drains vmcnt before s_barrier
    short8 af[4], bv[4];
#pragma unroll
    for (int i = 0; i < 4; ++i) af[i] = *(const short8*)&ldsA[(wm + i * 16 + lr) * 32 + lq * 8];
#pragma unroll
    for (int j = 0; j < 4; ++j) bv[j] = *(const short8*)&ldsB[(wn + j * 16 + lr) * 32 + lq * 8];
#pragma unroll
    for (int i = 0; i < 4; ++i)
#pragma unroll
      for (int j = 0; j < 4; ++j)
        acc[i][j] = __builtin_amdgcn_mfma_f32_16x16x32_bf16(af[i], bv[j], acc[i][j], 0, 0, 0);
  }
#pragma unroll
  for (int i = 0; i < 4; ++i)
#pragma unroll
    for (int j = 0; j < 4; ++j) {
      const int gc = nt * 128 + wn + j * 16 + lr;
      const int gr = mt * 128 + wm + i * 16 + lq * 4;   // C/D: row=(lane>>4)*4+reg, col=lane&15
#pragma unroll
      for (int r = 0; r < 4; ++r)
        C[(size_t)(gr + r) * CDIM + gc] = f2bf(acc[i][j][r]);
    }
}

// ---------- fully fused routing loop: 3x (scores -> softmax -> weighted sum), pointwise in bn ----------
__global__ __launch_bounds__(192) void k_iter3(const unsigned short* __restrict__ xw1b,
                                               const unsigned short* __restrict__ cw1,
                                               const unsigned short* __restrict__ pw1b,
                                               const unsigned short* __restrict__ projb,
                                               const float* __restrict__ b1,
                                               const float* __restrict__ w2,
                                               float* __restrict__ outc,
                                               float* __restrict__ outr) {
  __shared__ float red[3][NVIEW];
  __shared__ float aa[NVIEW];
  const int bn = blockIdx.x, t = threadIdx.x, wid = t >> 6, lane = t & 63;
  const int h = t * 4;
  const float4 bv = *(const float4*)(b1 + h);
  const float4 wv = *(const float4*)(w2 + h);
  float cw[4];
  { uint2 c = *(const uint2*)(cw1 + (size_t)bn * CDIM + h);
    cw[0] = bf_lo(c.x); cw[1] = bf_hi(c.x); cw[2] = bf_lo(c.y); cw[3] = bf_hi(c.y); }
  float xw[NVIEW][4], pf[NVIEW][4];
#pragma unroll
  for (int v = 0; v < NVIEW; ++v) {
    uint2 q = *(const uint2*)(xw1b + ((size_t)v * BN_TOT + bn) * CDIM + h);
    xw[v][0] = bf_lo(q.x) + bv.x; xw[v][1] = bf_hi(q.x) + bv.y;
    xw[v][2] = bf_lo(q.y) + bv.z; xw[v][3] = bf_hi(q.y) + bv.w;
    uint2 p = *(const uint2*)(pw1b + ((size_t)v * BN_TOT + bn) * CDIM + h);
    pf[v][0] = bf_lo(p.x); pf[v][1] = bf_hi(p.x);
    pf[v][2] = bf_lo(p.y); pf[v][3] = bf_hi(p.y);
  }
  for (int it = 0; it < 3; ++it) {
    float part[NVIEW];
#pragma unroll
    for (int v = 0; v < NVIEW; ++v) {
      float p;
      p = wv.x * ftanh(xw[v][0] + cw[0]);
      p = fmaf(wv.y, ftanh(xw[v][1] + cw[1]), p);
      p = fmaf(wv.z, ftanh(xw[v][2] + cw[2]), p);
      p = fmaf(wv.w, ftanh(xw[v][3] + cw[3]), p);
      part[v] = p;
    }
#pragma unroll
    for (int off = 32; off > 0; off >>= 1)
#pragma unroll
      for (int v = 0; v < NVIEW; ++v) part[v] += __shfl_down(part[v], off);
    if (lane == 0)
#pragma unroll
      for (int v = 0; v < NVIEW; ++v) red[wid][v] = part[v];
    __syncthreads();
    if (t == 0) {
      float s[NVIEW];
#pragma unroll
      for (int v = 0; v < NVIEW; ++v) s[v] = red[0][v] + red[1][v] + red[2][v];
      float m = s[0];
#pragma unroll
      for (int v = 1; v < NVIEW; ++v) m = fmaxf(m, s[v]);
      float a[NVIEW], sum = 0.f;
#pragma unroll
      for (int v = 0; v < NVIEW; ++v) { a[v] = __expf(s[v] - m); sum += a[v]; }
      const float inv = 1.f / sum;
#pragma unroll
      for (int v = 0; v < NVIEW; ++v) { a[v] *= inv; aa[v] = a[v]; }
      if (it == 2) {
        float ent = 0.f;
#pragma unroll
        for (int v = 0; v < NVIEW; ++v) ent -= a[v] * logf(a[v] + 1e-8f);
        outr[bn] = 1.f - ent * 0.6213349345596119f;  // 1/ln(5)
      }
    }
    __syncthreads();
    if (it < 2) {
      float n0 = 0, n1 = 0, n2 = 0, n3 = 0;
#pragma unroll
      for (int v = 0; v < NVIEW; ++v) {
        const float av = aa[v];
        n0 = fmaf(av, pf[v][0], n0); n1 = fmaf(av, pf[v][1], n1);
        n2 = fmaf(av, pf[v][2], n2); n3 = fmaf(av, pf[v][3], n3);
      }
      cw[0] = n0; cw[1] = n1; cw[2] = n2; cw[3] = n3;
    } else {
      float r0 = 0, r1 = 0, r2 = 0, r3 = 0;
#pragma unroll
      for (int v = 0; v < NVIEW; ++v) {
        const float av = aa[v];
        uint2 p = *(const uint2*)(projb + ((size_t)v * BN_TOT + bn) * CDIM + h);
        r0 = fmaf(av, bf_lo(p.x), r0); r1 = fmaf(av, bf_hi(p.x), r1);
        r2 = fmaf(av, bf_lo(p.y), r2); r3 = fmaf(av, bf_hi(p.y), r3);
      }
      float4 of; of.x = r0; of.y = r1; of.z = r2; of.w = r3;
      *(float4*)(outc + (size_t)bn * CDIM + h) = of;
    }
  }
}

extern "C" void kernel_launch(void* const* d_in, const int* in_sizes, int n_in,
                              void* d_out, int out_size, void* d_ws, size_t ws_size,
                              hipStream_t stream) {
  (void)in_sizes; (void)n_in; (void)out_size; (void)ws_size;
  const float* x  = (const float*)d_in[0];   // [B,V,N,C] fp32
  const float* wv = (const float*)d_in[1];   // [V,C,C]
  const float* w1 = (const float*)d_in[2];   // [2C,H]
  const float* b1 = (const float*)d_in[3];   // [H]
  const float* w2 = (const float*)d_in[4];   // [H,1]
  // d_in[5] = b2: uniform shift over views -> softmax-invariant, unused.

  // workspace: 86,016,000 ushorts = 172 MB (known-safe; 232 MB overflowed in round 6)
  unsigned short* ws   = (unsigned short*)d_ws;
  unsigned short* wvT  = ws;                             //  2,949,120  [V][d][c]
  unsigned short* w1aT = ws + 2949120;                   //    589,824
  unsigned short* w1bT = ws + 3538944;                   //    589,824
  unsigned short* xb   = ws + 4128768;                   // 24,084,480  [V,BN,C]; dead after GEMM A
  unsigned short* pw1b = ws + 4128768;                   //   (aliased onto xb)
  unsigned short* projb= ws + 28213248;                  // 24,084,480
  unsigned short* xw1b = ws + 52297728;                  // 24,084,480
  unsigned short* cb   = ws + 76382208;                  //  4,816,896
  unsigned short* cw1  = ws + 81199104;                  //  4,816,896  (end: 86,016,000)

  float* outc = (float*)d_out;                           // c [B,N,C] fp32
  float* outr = outc + SLAB;                             // r [B,N]   fp32

  k_tr<<<dim3(24, 24, 7), dim3(32, 8), 0, stream>>>(wv, w1, wvT, w1aT, w1bT);
  k_cvt_mean<<<BN_TOT, 192, 0, stream>>>(x, xb, cb);
  // GEMM A: proj_v = xb_v @ wv_v ; xw1_v = xb_v @ w1a ; cw1_0 = cb @ w1b
  // 3234 works, chunk 405/XCD, grid 3240 (6 idle)
  gemm_bt<0, 3234, 405><<<3240, 256, 0, stream>>>(xb, cb, wvT, w1aT, w1bT, projb, xw1b, cw1);
  // GEMM B: pw1b_v = proj_v @ w1b  (xb memory reused; 1470 works, chunk 184, grid 1472)
  gemm_bt<1, 1470, 184><<<1472, 256, 0, stream>>>(projb, nullptr, nullptr, nullptr, w1bT,
                                                  pw1b, nullptr, nullptr);
  // fused routing: 3 iterations pointwise in (b,n), no GEMMs (linearity of @w1b)
  k_iter3<<<BN_TOT, 192, 0, stream>>>(xw1b, cw1, pw1b, projb, b1, w2, outc, outr);
}